// Round 10
// baseline (372.055 us; speedup 1.0000x reference)
//
#include <hip/hip_runtime.h>

// ---------------------------------------------------------------------------
// CausalAttention: B=8, S=2048, D=1024, fp32 in, fp32 out.
// Round 15: r14 + pv converted to the 256^2 8-wave core (r14's A/B showed it
// is ~2x better per-FLOP than the 128^2 4-wave core).
//   - pv: grid 4(n)x8(by)x8(bz)=256 blocks = 1/CU all-resident, NKT=(by+1)*8;
//     XCD remap: bz = XCD (Vt panel fits that XCD's 4MB L2), the 4 n-blocks
//     sharing a P-prefix land on one XCD.
//   - softmax prefix granularity 128 -> 256 (pv reads the 256-aligned causal
//     prefix; diag-tile -inf region must be softmaxed to 0, else -inf -> NaN).
//   - proj / scores / cvt byte-identical to r14 (368.3 µs baseline).
//   ws: Q 32 | K 32 | Vt 32 | Sc 64  (xh@Sc+0 32MB, Wh@Sc+32MB 6MB)
// ---------------------------------------------------------------------------

typedef _Float16 v8h __attribute__((ext_vector_type(8)));
typedef _Float16 v4h __attribute__((ext_vector_type(4)));
typedef float    v4f __attribute__((ext_vector_type(4)));

#define BM 256
#define BN 256

__device__ __forceinline__ void async16(const _Float16* g, _Float16* l) {
  __builtin_amdgcn_global_load_lds(
      (__attribute__((address_space(1))) void*)(void*)g,
      (__attribute__((address_space(3))) void*)l, 16, 0, 0);
}

__device__ __forceinline__ void rd_a(const _Float16* U, int offA0, int base,
                                     v8h a[4]) {
#pragma unroll
  for (int i = 0; i < 4; ++i) a[i] = *(const v8h*)(U + offA0 + (base + i) * 512);
}
__device__ __forceinline__ void rd_b(const _Float16* U, int offB0, v8h b[4]) {
#pragma unroll
  for (int j = 0; j < 4; ++j) b[j] = *(const v8h*)(U + offB0 + j * 512);
}

__device__ __forceinline__ void mfma16(const v8h a[4], const v8h b[4],
                                       v4f (*accr)[4]) {
  __builtin_amdgcn_s_setprio(1);
#pragma unroll
  for (int i = 0; i < 4; ++i)
#pragma unroll
    for (int j = 0; j < 4; ++j)
      accr[i][j] = __builtin_amdgcn_mfma_f32_16x16x32_f16(a[i], b[j],
                                                          accr[i][j], 0, 0, 0);
  __builtin_amdgcn_s_setprio(0);
}

#define VM8 asm volatile("s_waitcnt vmcnt(8)" ::: "memory")
#define VM4 asm volatile("s_waitcnt vmcnt(4)" ::: "memory")
#define VM0 asm volatile("s_waitcnt vmcnt(0)" ::: "memory")
#define LG8                                                                  \
  asm volatile("s_waitcnt lgkmcnt(8)" ::: "memory");                         \
  __builtin_amdgcn_sched_barrier(0)
#define LG4                                                                  \
  asm volatile("s_waitcnt lgkmcnt(4)" ::: "memory");                         \
  __builtin_amdgcn_sched_barrier(0)
#define LG0                                                                  \
  asm volatile("s_waitcnt lgkmcnt(0)" ::: "memory");                         \
  __builtin_amdgcn_sched_barrier(0)
#define BAR __builtin_amdgcn_s_barrier()
#define SBAR __builtin_amdgcn_sched_barrier(0)

// ---------------------------------------------------------------------------
// 256^2 / 8-wave GEMM loop (r10 form, measured best).  NKT >= 8, even.
// ---------------------------------------------------------------------------
__device__ __forceinline__ void gemm_loop(const _Float16* Ab, int lda,
                                          const _Float16* Bb, int ldb,
                                          int NKT, _Float16* lds,
                                          int w, int lane, int wr, int wc,
                                          int lr, int quad, v4f acc[8][4]) {
  const int offA0 = (wr + lr) * 32 + ((quad ^ (((wr + lr) >> 1) & 3)) * 8);
  const int offB0 = 8192 + (wc + lr) * 32 + ((quad ^ (((wc + lr) >> 1) & 3)) * 8);

  const int u0 = w * 128 + lane;
  const int u1 = u0 + 64;
  const int r0 = u0 >> 2, c0 = (u0 & 3) ^ ((r0 >> 1) & 3);
  const int r1 = u1 >> 2, c1 = (u1 & 3) ^ ((r1 >> 1) & 3);
  const _Float16* pA0 = Ab + (size_t)r0 * lda + c0 * 8;
  const _Float16* pA1 = Ab + (size_t)r1 * lda + c1 * 8;
  const _Float16* pB0 = Bb + (size_t)r0 * ldb + c0 * 8;
  const _Float16* pB1 = Bb + (size_t)r1 * ldb + c1 * 8;
  const int dA0 = (w * 128) * 8;
  const int dA1 = (w * 128 + 64) * 8;

#define STAGE(T)                                                             \
  do {                                                                       \
    _Float16* Ld = lds + ((T) & 3) * 16384;                                  \
    async16(pA0 + (T) * 32, Ld + dA0);                                       \
    async16(pB0 + (T) * 32, Ld + 8192 + dA0);                                \
    async16(pA1 + (T) * 32, Ld + dA1);                                       \
    async16(pB1 + (T) * 32, Ld + 8192 + dA1);                                \
  } while (0)
#define SL(T) (lds + ((T) & 3) * 16384)

  v8h aLo[4], aHi[4], bE[4], bO[4];

  STAGE(0);
  STAGE(1);
  STAGE(2);
  VM8;
  BAR;
  rd_a(SL(0), offA0, 0, aLo);
  rd_b(SL(0), offB0, bE);

  for (int t2 = 0; t2 < NKT - 4; t2 += 2) {
    VM8; BAR;
    rd_a(SL(t2), offA0, 4, aHi);
    STAGE(t2 + 3);
    LG4; mfma16(aLo, bE, &acc[0]);
    VM8; BAR;
    rd_a(SL(t2 + 1), offA0, 0, aLo);
    rd_b(SL(t2 + 1), offB0, bO);
    LG8; mfma16(aHi, bE, &acc[4]);
    VM8; BAR;
    rd_a(SL(t2 + 1), offA0, 4, aHi);
    STAGE(t2 + 4);
    LG4; mfma16(aLo, bO, &acc[0]);
    VM8; BAR;
    rd_a(SL(t2 + 2), offA0, 0, aLo);
    rd_b(SL(t2 + 2), offB0, bE);
    LG8; mfma16(aHi, bO, &acc[4]);
  }

  VM8; BAR;
  rd_a(SL(NKT - 4), offA0, 4, aHi);
  STAGE(NKT - 1);
  LG4; mfma16(aLo, bE, &acc[0]);
  VM8; BAR;
  rd_a(SL(NKT - 3), offA0, 0, aLo);
  rd_b(SL(NKT - 3), offB0, bO);
  LG8; mfma16(aHi, bE, &acc[4]);
  VM8; BAR;
  rd_a(SL(NKT - 3), offA0, 4, aHi);
  LG4; mfma16(aLo, bO, &acc[0]);
  VM4; BAR;
  rd_a(SL(NKT - 2), offA0, 0, aLo);
  rd_b(SL(NKT - 2), offB0, bE);
  LG8; mfma16(aHi, bO, &acc[4]);

  VM4; BAR;
  rd_a(SL(NKT - 2), offA0, 4, aHi);
  LG4; mfma16(aLo, bE, &acc[0]);
  VM0; BAR;
  rd_a(SL(NKT - 1), offA0, 0, aLo);
  rd_b(SL(NKT - 1), offB0, bO);
  LG8; mfma16(aHi, bE, &acc[4]);
  BAR;
  rd_a(SL(NKT - 1), offA0, 4, aHi);
  LG4; mfma16(aLo, bO, &acc[0]);
  LG0; mfma16(aHi, bO, &acc[4]);
#undef STAGE
#undef SL
}

// Bijective XCD-aware swizzle (proj grid 768 % 8 == 0).
__device__ __forceinline__ void grid_swz(int& bx, int& by) {
  const int gx = gridDim.x;
  const int n = gx * gridDim.y;
  const int f = blockIdx.x + blockIdx.y * gx;
  const int s = (f & 7) * (n >> 3) + (f >> 3);
  bx = s % gx;
  by = s / gx;
}

// ---------------------------------------------------------------------------
// fp32 -> fp16, 8 elems/thread.
// ---------------------------------------------------------------------------
__global__ __launch_bounds__(256)
void cvt_f16(const float* __restrict__ src, _Float16* __restrict__ dst) {
  const int i = (blockIdx.x * 256 + threadIdx.x) * 8;
  float4 a = *(const float4*)(src + i);
  float4 b = *(const float4*)(src + i + 4);
  v8h o = {(_Float16)a.x, (_Float16)a.y, (_Float16)a.z, (_Float16)a.w,
           (_Float16)b.x, (_Float16)b.y, (_Float16)b.z, (_Float16)b.w};
  *(v8h*)(dst + i) = o;
}

__global__ __launch_bounds__(256)
void cvt_f16_w(const float* __restrict__ Wq, const float* __restrict__ Wk,
               const float* __restrict__ Wv, _Float16* __restrict__ dst) {
  const int bid = blockIdx.x;
  const int m = bid >> 9;
  const float* src = (m == 0) ? Wq : (m == 1) ? Wk : Wv;
  const int i = ((bid & 511) * 256 + threadIdx.x) * 8;
  float4 a = *(const float4*)(src + i);
  float4 b = *(const float4*)(src + i + 4);
  v8h o = {(_Float16)a.x, (_Float16)a.y, (_Float16)a.z, (_Float16)a.w,
           (_Float16)b.x, (_Float16)b.y, (_Float16)b.z, (_Float16)b.w};
  *(v8h*)(dst + (size_t)m * 1048576 + i) = o;
}

// ---------------------------------------------------------------------------
// Projection (r10 form, unchanged): C[m][n] = X[m][:].W[n][:], n packed Q|K|V.
// ---------------------------------------------------------------------------
__global__ __launch_bounds__(512, 2)
void proj_gemm(const _Float16* __restrict__ X, const _Float16* __restrict__ W,
               _Float16* __restrict__ Qb, _Float16* __restrict__ Kb,
               _Float16* __restrict__ Vt) {
  __shared__ _Float16 lds[65536];
  const int tid = threadIdx.x;
  int bx, by;
  grid_swz(bx, by);
  const int n0 = bx * BN, m0 = by * BM;
  const int which = n0 >> 10;
  const int nw = n0 & 1023;

  const int lane = tid & 63, w = tid >> 6;
  const int wr = (w >> 2) * 128, wc = (w & 3) * 64;
  const int lr = lane & 15, quad = lane >> 4;

  v4f acc[8][4];
#pragma unroll
  for (int i = 0; i < 8; ++i)
#pragma unroll
    for (int j = 0; j < 4; ++j) acc[i][j] = (v4f){0.f, 0.f, 0.f, 0.f};

  gemm_loop(X + (size_t)m0 * 1024, 1024, W + (size_t)n0 * 1024, 1024,
            32, lds, w, lane, wr, wc, lr, quad, acc);

#pragma unroll
  for (int i = 0; i < 8; ++i) {
    const int r0 = m0 + wr + i * 16 + quad * 4;
#pragma unroll
    for (int j = 0; j < 4; ++j) {
      const int cl = wc + j * 16 + lr;
      if (which < 2) {
        _Float16* dst = (which == 0) ? Qb : Kb;
        const int col = nw + cl;
#pragma unroll
        for (int rg = 0; rg < 4; ++rg)
          dst[(size_t)(r0 + rg) * 1024 + col] = (_Float16)acc[i][j][rg];
      } else {
        const int d = nw + cl;
        const int b = r0 >> 11, s = r0 & 2047;
        v4h o = {(_Float16)acc[i][j][0], (_Float16)acc[i][j][1],
                 (_Float16)acc[i][j][2], (_Float16)acc[i][j][3]};
        *(v4h*)(Vt + (size_t)b * 1024 * 2048 + (size_t)d * 2048 + s) = o;
      }
    }
  }
}

// ---------------------------------------------------------------------------
// Scores (unchanged from r14): 256^2 core, triangular 288-block grid.
// ---------------------------------------------------------------------------
__global__ __launch_bounds__(512, 2)
void scores_gemm(const _Float16* __restrict__ Q, const _Float16* __restrict__ K,
                 _Float16* __restrict__ Sc) {
  __shared__ _Float16 lds[65536];
  const int tid = threadIdx.x;
  const int f = blockIdx.x;                      // 0..287
  const int s = (f & 7) * 36 + (f >> 3);         // bijective, 288 = 8*36
  const int bz = s / 36;
  const int t1d = s % 36;                        // 0..35 lower-tri index

  int by = 0;
  while ((by + 1) * (by + 2) / 2 <= t1d) ++by;   // <= 7 iters, wave-uniform
  const int bx = t1d - by * (by + 1) / 2;        // 0..by

  const int m0 = by * 256, n0 = bx * 256;
  _Float16* Cb = Sc + (size_t)bz * 2048 * 2048;
  const _Float16* Qz = Q + (size_t)bz * 2048 * 1024;
  const _Float16* Kz = K + (size_t)bz * 2048 * 1024;

  const int lane = tid & 63, w = tid >> 6;
  const int wr = (w >> 2) * 128, wc = (w & 3) * 64;
  const int lr = lane & 15, quad = lane >> 4;

  v4f acc[8][4];
#pragma unroll
  for (int i = 0; i < 8; ++i)
#pragma unroll
    for (int j = 0; j < 4; ++j) acc[i][j] = (v4f){0.f, 0.f, 0.f, 0.f};

  gemm_loop(Qz + (size_t)m0 * 1024, 1024, Kz + (size_t)n0 * 1024, 1024,
            32, lds, w, lane, wr, wc, lr, quad, acc);

  const _Float16 ninf = (_Float16)(-__builtin_inff());
  const bool diag = (bx == by);
#pragma unroll
  for (int i = 0; i < 8; ++i) {
    const int r0 = m0 + wr + i * 16 + quad * 4;
#pragma unroll
    for (int j = 0; j < 4; ++j) {
      const int cc = n0 + wc + j * 16 + lr;
#pragma unroll
      for (int rg = 0; rg < 4; ++rg) {
        const int rr = r0 + rg;
        _Float16 v = (_Float16)acc[i][j][rg];
        Cb[(size_t)rr * 2048 + cc] = (diag && cc > rr) ? ninf : v;
      }
    }
  }
}

// ---------------------------------------------------------------------------
// Row softmax in place (f16); valid prefix [0, (q/256+1)*256) — 256-granular
// to match pv's read range (diag-tile -inf region becomes proper zeros).
// ---------------------------------------------------------------------------
__global__ __launch_bounds__(256)
void softmax_rows(_Float16* __restrict__ Sc) {
  _Float16* base = Sc + (size_t)blockIdx.x * 2048;
  const int q = blockIdx.x & 2047;
  const int ktile = ((q >> 8) + 1) << 8;
  const int tid = threadIdx.x;
  const int lane = tid & 63, w = tid >> 6;
  const bool active = tid * 8 < ktile;

  float f[8];
  if (active) {
    v8h pv = *(const v8h*)(base + tid * 8);
#pragma unroll
    for (int j = 0; j < 8; ++j) f[j] = (float)pv[j];
  } else {
#pragma unroll
    for (int j = 0; j < 8; ++j) f[j] = -__builtin_inff();
  }

  float mx = f[0];
#pragma unroll
  for (int j = 1; j < 8; ++j) mx = fmaxf(mx, f[j]);
#pragma unroll
  for (int off = 32; off; off >>= 1) mx = fmaxf(mx, __shfl_xor(mx, off));
  __shared__ float redm[4], reds[4];
  if (lane == 0) redm[w] = mx;
  __syncthreads();
  mx = fmaxf(fmaxf(redm[0], redm[1]), fmaxf(redm[2], redm[3]));

  const float scale = 0.03125f;                  // 1/sqrt(1024)
  float e[8], s = 0.f;
#pragma unroll
  for (int j = 0; j < 8; ++j) {
    e[j] = __expf((f[j] - mx) * scale);
    s += e[j];
  }
#pragma unroll
  for (int off = 32; off; off >>= 1) s += __shfl_xor(s, off);
  if (lane == 0) reds[w] = s;
  __syncthreads();
  s = reds[0] + reds[1] + reds[2] + reds[3];
  const float inv = 1.0f / s;
  if (active) {
    v8h pv;
#pragma unroll
    for (int j = 0; j < 8; ++j) pv[j] = (_Float16)(e[j] * inv);
    *(v8h*)(base + tid * 8) = pv;
  }
}

// ---------------------------------------------------------------------------
// Out (fp32): pv on the 256^2 core.  256 blocks = 1/CU.  Block b:
// bz = b&7 (one batch per XCD -> Vt panel L2-resident), s = b>>3,
// by = s>>2, n = s&3.  NKT = (by+1)*8 in [8,64].
// ---------------------------------------------------------------------------
__global__ __launch_bounds__(512, 2)
void pv_gemm(const _Float16* __restrict__ P, const _Float16* __restrict__ Vt,
             float* __restrict__ Out) {
  __shared__ _Float16 lds[65536];
  const int tid = threadIdx.x;
  const int b = blockIdx.x;                      // 0..255
  const int bz = b & 7;
  const int s = b >> 3;                          // 0..31
  const int by = s >> 2;                         // 0..7
  const int nn = s & 3;                          // 0..3
  const int m0 = by * 256, n0 = nn * 256;
  const int NKT = (by + 1) * 8;

  const _Float16* Pb = P + (size_t)bz * 2048 * 2048;
  const _Float16* Vb = Vt + (size_t)bz * 1024 * 2048;
  float* Cb = Out + (size_t)bz * 2048 * 1024;

  const int lane = tid & 63, w = tid >> 6;
  const int wr = (w >> 2) * 128, wc = (w & 3) * 64;
  const int lr = lane & 15, quad = lane >> 4;

  v4f acc[8][4];
#pragma unroll
  for (int i = 0; i < 8; ++i)
#pragma unroll
    for (int j = 0; j < 4; ++j) acc[i][j] = (v4f){0.f, 0.f, 0.f, 0.f};

  gemm_loop(Pb + (size_t)m0 * 2048, 2048, Vb + (size_t)n0 * 2048, 2048,
            NKT, lds, w, lane, wr, wc, lr, quad, acc);

#pragma unroll
  for (int i = 0; i < 8; ++i) {
    const int r0 = m0 + wr + i * 16 + quad * 4;
#pragma unroll
    for (int j = 0; j < 4; ++j) {
      const int cc = n0 + wc + j * 16 + lr;
#pragma unroll
      for (int rg = 0; rg < 4; ++rg)
        Cb[(size_t)(r0 + rg) * 1024 + cc] = acc[i][j][rg];   // fp32 store
    }
  }
}

// ---------------------------------------------------------------------------
extern "C" void kernel_launch(void* const* d_in, const int* in_sizes, int n_in,
                              void* d_out, int out_size, void* d_ws, size_t ws_size,
                              hipStream_t stream) {
  const int B = 8, S = 2048, D = 1024;
  const int M = B * S;                           // 16384
  const float* x  = (const float*)d_in[0];
  const float* Wq = (const float*)d_in[1];
  const float* Wk = (const float*)d_in[2];
  const float* Wv = (const float*)d_in[3];
  float* out = (float*)d_out;

  char* ws = (char*)d_ws;
  _Float16* Qb = (_Float16*)ws;                          // [M][1024]
  _Float16* Kb = (_Float16*)(ws + (size_t)33554432);     // [M][1024]
  _Float16* Vt = (_Float16*)(ws + (size_t)67108864);     // [B][1024][2048]
  _Float16* Sc = (_Float16*)(ws + (size_t)100663296);    // [B][2048][2048]
  _Float16* xh = Sc;                                     // alias (dead later)
  _Float16* Wh = Sc + (size_t)M * D;                     // alias

  // 1) fp32 -> fp16 converts
  cvt_f16<<<(M * D) / 2048, 256, 0, stream>>>(x, xh);
  cvt_f16_w<<<1536, 256, 0, stream>>>(Wq, Wk, Wv, Wh);

  // 2) QKV projection (256^2 GEMM)
  proj_gemm<<<dim3(12, M / BM, 1), 512, 0, stream>>>(xh, Wh, Qb, Kb, Vt);

  // 3) raw scores: 256^2 core, triangular 288-block grid
  scores_gemm<<<288, 512, 0, stream>>>(Qb, Kb, Sc);

  // 4) softmax on 256-aligned valid prefix
  softmax_rows<<<B * S, 256, 0, stream>>>(Sc);

  // 5) out = P @ Vt, 256^2 core, 256 blocks (1/CU), XCD-resident Vt
  pv_gemm<<<256, 512, 0, stream>>>(Sc, Vt, out);
}